// Round 1
// baseline (831.527 us; speedup 1.0000x reference)
//
#include <hip/hip_runtime.h>

#define N_TOK 2048
#define DIM   1024
#define NE    8
#define HID   2048
#define NA    6144        // 4096 routed assignments + 2048 shared
#define A_SHARED 4096
#define OUT_HID (N_TOK * DIM)   // 2097152

typedef float v4f __attribute__((ext_vector_type(4)));
typedef short v8s __attribute__((ext_vector_type(8)));

// ---- workspace layout (bytes) ----
#define OFF_XBF   0ull                          // 2048*1024*2 = 4194304
#define OFF_H     4194304ull                    // 6144*2048*2 = 25165824
#define OFF_TOK   (OFF_H + 25165824ull)         // 6144*4
#define OFF_WL    (OFF_TOK + 24576ull)          // 6144*4
#define OFF_IDX   (OFF_WL + 24576ull)           // 2048*2*4
#define OFF_TW    (OFF_IDX + 16384ull)          // 2048*2*4
#define OFF_STATS (OFF_TW + 16384ull)

struct Stats {
  int counts[NE];
  int fill[NE];
  int offs[NE + 2];
  float z2;
  float psum[NE];
};

__device__ __forceinline__ unsigned short f2bf(float f) {
  union { float f; unsigned u; } v; v.f = f;
  unsigned r = v.u + 0x7FFFu + ((v.u >> 16) & 1u);
  return (unsigned short)(r >> 16);
}
__device__ __forceinline__ unsigned pack2bf(float a, float b) {
  return (unsigned)f2bf(a) | ((unsigned)f2bf(b) << 16);
}

// ---- cast x to bf16 ----
__global__ __launch_bounds__(256) void cast_x_kernel(const float* __restrict__ x,
                                                     unsigned short* __restrict__ xbf) {
  int i = blockIdx.x * 256 + threadIdx.x;      // 524288 threads, 4 elems each
  float4 v = ((const float4*)x)[i];
  uint2 o;
  o.x = pack2bf(v.x, v.y);
  o.y = pack2bf(v.z, v.w);
  ((uint2*)xbf)[i] = o;
}

// ---- router: fp32 logits, top2, softmax weights, z-loss + load-balance stats ----
__global__ __launch_bounds__(256) void router_kernel(
    const float* __restrict__ x, const float* __restrict__ rw, const float* __restrict__ rb,
    int* __restrict__ idxbuf, float* __restrict__ twbuf, Stats* __restrict__ st) {
  int lane = threadIdx.x & 63;
  int wv = threadIdx.x >> 6;
  int n = blockIdx.x * 4 + wv;

  float acc[NE];
#pragma unroll
  for (int e = 0; e < NE; ++e) acc[e] = 0.f;

  const float4* x4 = (const float4*)(x + (size_t)n * DIM);
#pragma unroll
  for (int q = 0; q < 4; ++q) {
    float4 xv = x4[q * 64 + lane];
#pragma unroll
    for (int e = 0; e < NE; ++e) {
      const float4* w4 = (const float4*)(rw + (size_t)e * DIM);
      float4 wvv = w4[q * 64 + lane];
      acc[e] += xv.x * wvv.x + xv.y * wvv.y + xv.z * wvv.z + xv.w * wvv.w;
    }
  }
#pragma unroll
  for (int off = 32; off; off >>= 1) {
#pragma unroll
    for (int e = 0; e < NE; ++e) acc[e] += __shfl_xor(acc[e], off);
  }

  // all lanes hold the full 8 logits now
  float mx = acc[0];
#pragma unroll
  for (int e = 1; e < NE; ++e) mx = fmaxf(mx, acc[e]);
  float pr[NE];
  float es = 0.f;
#pragma unroll
  for (int e = 0; e < NE; ++e) { pr[e] = __expf(acc[e] - mx); es += pr[e]; }
  float inv = 1.f / es;
#pragma unroll
  for (int e = 0; e < NE; ++e) pr[e] *= inv;
  float z = mx + __logf(es);

  // top-2 on biased logits (stable: strict > keeps lowest index on ties, matching top_k)
  float b0 = -1e30f; int i0 = 0;
#pragma unroll
  for (int e = 0; e < NE; ++e) {
    float bb = acc[e] + rb[e];
    if (bb > b0) { b0 = bb; i0 = e; }
  }
  float b1 = -1e30f; int i1 = 0;
#pragma unroll
  for (int e = 0; e < NE; ++e) {
    if (e == i0) continue;
    float bb = acc[e] + rb[e];
    if (bb > b1) { b1 = bb; i1 = e; }
  }
  // softmax over the two raw logits
  float l0 = acc[i0], l1 = acc[i1];
  float m2 = fmaxf(l0, l1);
  float e0 = __expf(l0 - m2), e1 = __expf(l1 - m2);
  float den = 1.f / (e0 + e1);
  float w0 = e0 * den, w1 = e1 * den;

  __shared__ float redp[4][9];
  __shared__ int redc[4][8];
  if (lane == 0) {
    idxbuf[n * 2] = i0; idxbuf[n * 2 + 1] = i1;
    twbuf[n * 2] = w0;  twbuf[n * 2 + 1] = w1;
#pragma unroll
    for (int e = 0; e < NE; ++e) redp[wv][e] = pr[e];
    redp[wv][8] = z * z;
#pragma unroll
    for (int e = 0; e < NE; ++e) redc[wv][e] = (e == i0) + (e == i1);
  }
  __syncthreads();
  int t = threadIdx.x;
  if (t < 9) {
    float s = redp[0][t] + redp[1][t] + redp[2][t] + redp[3][t];
    if (t < 8) atomicAdd(&st->psum[t], s);
    else       atomicAdd(&st->z2, s);
  } else if (t >= 16 && t < 24) {
    int e = t - 16;
    atomicAdd(&st->counts[e], redc[0][e] + redc[1][e] + redc[2][e] + redc[3][e]);
  }
}

// ---- scan: expert offsets + scalar outputs ----
__global__ void scan_kernel(Stats* __restrict__ st, float* __restrict__ out) {
  if (threadIdx.x == 0 && blockIdx.x == 0) {
    int o = 0;
#pragma unroll
    for (int e = 0; e < NE; ++e) { st->offs[e] = o; o += st->counts[e]; }
    st->offs[NE] = o;              // == 4096
    st->offs[NE + 1] = o + N_TOK;  // == 6144
    float zl = st->z2 / (float)N_TOK * 1e-4f;
    float lb = 0.f;
#pragma unroll
    for (int e = 0; e < NE; ++e)
      lb += (st->psum[e] / (float)N_TOK) * ((float)st->counts[e] / (float)N_TOK);
    lb *= (float)NE;
    out[OUT_HID + 0] = 0.f;   // aux_loss
    out[OUT_HID + 1] = zl;    // router_z_loss
    out[OUT_HID + 2] = lb;    // load_balance
  }
}

// ---- scatter: build per-expert assignment lists (+ shared as expert 8) ----
__global__ __launch_bounds__(256) void scatter_kernel(
    const int* __restrict__ idxbuf, const float* __restrict__ twbuf,
    Stats* __restrict__ st, int* __restrict__ tok, float* __restrict__ wl) {
  int n = blockIdx.x * 256 + threadIdx.x;
#pragma unroll
  for (int k = 0; k < 2; ++k) {
    int e = idxbuf[n * 2 + k];
    int pos = st->offs[e] + atomicAdd(&st->fill[e], 1);
    tok[pos] = n;
    wl[pos] = twbuf[n * 2 + k];
  }
  tok[A_SHARED + n] = n;
  wl[A_SHARED + n] = 1.f;
}

// ---- gate+up grouped GEMM: h = silu(X Gw^T) * (X Uw^T), bf16 out ----
__global__ __launch_bounds__(256) void gateup_kernel(
    const float* __restrict__ gate_w, const float* __restrict__ up_w,
    const float* __restrict__ shg, const float* __restrict__ shu,
    const unsigned short* __restrict__ xbf, const int* __restrict__ tok,
    const Stats* __restrict__ st, unsigned short* __restrict__ hbuf) {
  int e = blockIdx.z;
  int seg0 = st->offs[e];
  int cnt = st->offs[e + 1] - seg0;
  int m0 = blockIdx.x * 64;
  if (m0 >= cnt) return;
  int n0 = blockIdx.y * 64;

  const float* gw = (e < NE) ? gate_w + (size_t)e * HID * DIM : shg;
  const float* uw = (e < NE) ? up_w + (size_t)e * HID * DIM : shu;

  __shared__ alignas(16) unsigned short As[64 * 40];
  __shared__ alignas(16) unsigned short Bg[64 * 40];
  __shared__ alignas(16) unsigned short Bu[64 * 40];

  int tid = threadIdx.x, lane = tid & 63, wv = tid >> 6;
  int srow = tid >> 2, sp = tid & 3;

  bool av_ok = (m0 + srow) < cnt;
  const unsigned short* aptr = xbf;
  if (av_ok) aptr = xbf + (size_t)tok[seg0 + m0 + srow] * DIM + sp * 8;
  const float* gp = gw + (size_t)(n0 + srow) * DIM + sp * 8;
  const float* up = uw + (size_t)(n0 + srow) * DIM + sp * 8;

  v4f ag[4], au[4];
#pragma unroll
  for (int j = 0; j < 4; ++j) { ag[j] = (v4f){0.f,0.f,0.f,0.f}; au[j] = (v4f){0.f,0.f,0.f,0.f}; }

  unsigned aoff = srow * 40 + sp * 8;
  unsigned foffA = (wv * 16 + (lane & 15)) * 40 + (lane >> 4) * 8;

  for (int k0 = 0; k0 < DIM; k0 += 32) {
    uint4 a = make_uint4(0u, 0u, 0u, 0u);
    if (av_ok) a = *(const uint4*)(aptr + k0);
    float4 g0 = *(const float4*)(gp + k0);
    float4 g1 = *(const float4*)(gp + k0 + 4);
    float4 u0 = *(const float4*)(up + k0);
    float4 u1 = *(const float4*)(up + k0 + 4);
    *(uint4*)&As[aoff] = a;
    uint4 bg;
    bg.x = pack2bf(g0.x, g0.y); bg.y = pack2bf(g0.z, g0.w);
    bg.z = pack2bf(g1.x, g1.y); bg.w = pack2bf(g1.z, g1.w);
    *(uint4*)&Bg[aoff] = bg;
    uint4 bu;
    bu.x = pack2bf(u0.x, u0.y); bu.y = pack2bf(u0.z, u0.w);
    bu.z = pack2bf(u1.x, u1.y); bu.w = pack2bf(u1.z, u1.w);
    *(uint4*)&Bu[aoff] = bu;
    __syncthreads();

    v8s af = *(const v8s*)&As[foffA];
#pragma unroll
    for (int j = 0; j < 4; ++j) {
      unsigned fb = (j * 16 + (lane & 15)) * 40 + (lane >> 4) * 8;
      v8s bgf = *(const v8s*)&Bg[fb];
      ag[j] = __builtin_amdgcn_mfma_f32_16x16x32_bf16(af, bgf, ag[j], 0, 0, 0);
      v8s buf2 = *(const v8s*)&Bu[fb];
      au[j] = __builtin_amdgcn_mfma_f32_16x16x32_bf16(af, buf2, au[j], 0, 0, 0);
    }
    __syncthreads();
  }

  int rb_ = (lane >> 4) * 4, col = lane & 15;
#pragma unroll
  for (int j = 0; j < 4; ++j) {
#pragma unroll
    for (int r = 0; r < 4; ++r) {
      int rl = wv * 16 + rb_ + r;
      if (m0 + rl < cnt) {
        float g = ag[j][r], u = au[j][r];
        float hv = g * u / (1.f + __expf(-g));   // silu(g) * u
        hbuf[(size_t)(seg0 + m0 + rl) * HID + n0 + j * 16 + col] = f2bf(hv);
      }
    }
  }
}

// ---- down grouped GEMM: out[tok] += w * (h Dw^T) ----
__global__ __launch_bounds__(256) void down_kernel(
    const float* __restrict__ down_w, const float* __restrict__ shd,
    const unsigned short* __restrict__ hbuf, const int* __restrict__ tok,
    const float* __restrict__ wl, const Stats* __restrict__ st, float* __restrict__ out) {
  int e = blockIdx.z;
  int seg0 = st->offs[e];
  int cnt = st->offs[e + 1] - seg0;
  int m0 = blockIdx.x * 64;
  if (m0 >= cnt) return;
  int n0 = blockIdx.y * 64;   // over DIM

  const float* dw = (e < NE) ? down_w + (size_t)e * DIM * HID : shd;

  __shared__ alignas(16) unsigned short As[64 * 40];
  __shared__ alignas(16) unsigned short Bs[64 * 40];

  int tid = threadIdx.x, lane = tid & 63, wv = tid >> 6;
  int srow = tid >> 2, sp = tid & 3;

  bool av_ok = (m0 + srow) < cnt;
  const unsigned short* ap = hbuf + (size_t)(seg0 + m0 + srow) * HID + sp * 8;
  const float* bp = dw + (size_t)(n0 + srow) * HID + sp * 8;

  v4f acc[4];
#pragma unroll
  for (int j = 0; j < 4; ++j) acc[j] = (v4f){0.f,0.f,0.f,0.f};

  unsigned aoff = srow * 40 + sp * 8;
  unsigned foffA = (wv * 16 + (lane & 15)) * 40 + (lane >> 4) * 8;

  for (int k0 = 0; k0 < HID; k0 += 32) {
    uint4 a = make_uint4(0u, 0u, 0u, 0u);
    if (av_ok) a = *(const uint4*)(ap + k0);
    float4 b0 = *(const float4*)(bp + k0);
    float4 b1 = *(const float4*)(bp + k0 + 4);
    *(uint4*)&As[aoff] = a;
    uint4 bb;
    bb.x = pack2bf(b0.x, b0.y); bb.y = pack2bf(b0.z, b0.w);
    bb.z = pack2bf(b1.x, b1.y); bb.w = pack2bf(b1.z, b1.w);
    *(uint4*)&Bs[aoff] = bb;
    __syncthreads();

    v8s af = *(const v8s*)&As[foffA];
#pragma unroll
    for (int j = 0; j < 4; ++j) {
      v8s bf = *(const v8s*)&Bs[(j * 16 + (lane & 15)) * 40 + (lane >> 4) * 8];
      acc[j] = __builtin_amdgcn_mfma_f32_16x16x32_bf16(af, bf, acc[j], 0, 0, 0);
    }
    __syncthreads();
  }

  int rb_ = (lane >> 4) * 4, col = lane & 15;
  int tk[4]; float ww[4];
#pragma unroll
  for (int r = 0; r < 4; ++r) {
    int rl = wv * 16 + rb_ + r;
    if (m0 + rl < cnt) { tk[r] = tok[seg0 + m0 + rl]; ww[r] = wl[seg0 + m0 + rl]; }
    else tk[r] = -1;
  }
#pragma unroll
  for (int j = 0; j < 4; ++j) {
#pragma unroll
    for (int r = 0; r < 4; ++r) {
      if (tk[r] >= 0) {
        atomicAdd(&out[(size_t)tk[r] * DIM + n0 + j * 16 + col], acc[j][r] * ww[r]);
      }
    }
  }
}

extern "C" void kernel_launch(void* const* d_in, const int* in_sizes, int n_in,
                              void* d_out, int out_size, void* d_ws, size_t ws_size,
                              hipStream_t stream) {
  const float* x   = (const float*)d_in[0];
  const float* rw  = (const float*)d_in[1];
  const float* rb  = (const float*)d_in[2];
  const float* gw  = (const float*)d_in[3];
  const float* uw  = (const float*)d_in[4];
  const float* dw  = (const float*)d_in[5];
  const float* shg = (const float*)d_in[6];
  const float* shu = (const float*)d_in[7];
  const float* shd = (const float*)d_in[8];
  float* out = (float*)d_out;
  char* ws = (char*)d_ws;

  unsigned short* xbf  = (unsigned short*)(ws + OFF_XBF);
  unsigned short* hbuf = (unsigned short*)(ws + OFF_H);
  int*   tok  = (int*)(ws + OFF_TOK);
  float* wl   = (float*)(ws + OFF_WL);
  int*   idxb = (int*)(ws + OFF_IDX);
  float* twb  = (float*)(ws + OFF_TW);
  Stats* st   = (Stats*)(ws + OFF_STATS);

  hipMemsetAsync(d_out, 0, (size_t)out_size * sizeof(float), stream);
  hipMemsetAsync(st, 0, sizeof(Stats), stream);

  cast_x_kernel<<<2048, 256, 0, stream>>>(x, xbf);
  router_kernel<<<512, 256, 0, stream>>>(x, rw, rb, idxb, twb, st);
  scan_kernel<<<1, 64, 0, stream>>>(st, out);
  scatter_kernel<<<8, 256, 0, stream>>>(idxb, twb, st, tok, wl);
  gateup_kernel<<<dim3(32, 32, 9), 256, 0, stream>>>(gw, uw, shg, shu, xbf, tok, st, hbuf);
  down_kernel<<<dim3(32, 16, 9), 256, 0, stream>>>(dw, shd, hbuf, tok, wl, st, out);
}

// Round 2
// 592.735 us; speedup vs baseline: 1.4029x; 1.4029x over previous
//
#include <hip/hip_runtime.h>

#define N_TOK 2048
#define DIM   1024
#define NE    8
#define HID   2048
#define A_SHARED 4096
#define OUT_HID (N_TOK * DIM)

typedef float v4f __attribute__((ext_vector_type(4)));
typedef short v8s __attribute__((ext_vector_type(8)));

// ---- workspace layout (bytes) ----
#define OFF_XBF   0ull                           // 2048*1024*2        = 4,194,304
#define OFF_H     4194304ull                     // 6144*2048*2        = 25,165,824
#define OFF_GW    29360128ull                    // 9*2048*1024*2      = 37,748,736
#define OFF_UW    67108864ull
#define OFF_DW    104857600ull
#define OFF_TOK   142606336ull                   // 6144*4
#define OFF_WL    (OFF_TOK + 24576ull)
#define OFF_IDX   (OFF_WL + 24576ull)
#define OFF_TW    (OFF_IDX + 16384ull)
#define OFF_STATS (OFF_TW + 16384ull)

struct Stats {
  int counts[NE];
  int fill[NE];
  int offs[NE + 2];
  float z2;
  float psum[NE];
};

__device__ __forceinline__ unsigned short f2bf(float f) {
  union { float f; unsigned u; } v; v.f = f;
  unsigned r = v.u + 0x7FFFu + ((v.u >> 16) & 1u);
  return (unsigned short)(r >> 16);
}
__device__ __forceinline__ unsigned pack2bf(float a, float b) {
  return (unsigned)f2bf(a) | ((unsigned)f2bf(b) << 16);
}

__device__ __forceinline__ void async_lds16(const void* g, void* l) {
  __builtin_amdgcn_global_load_lds(
      (const __attribute__((address_space(1))) void*)g,
      (__attribute__((address_space(3))) void*)l, 16, 0, 0);
}

// ---- cast x to bf16 ----
__global__ __launch_bounds__(256) void cast_x_kernel(const float* __restrict__ x,
                                                     unsigned short* __restrict__ xbf) {
  int i = blockIdx.x * 256 + threadIdx.x;
  float4 v = ((const float4*)x)[i];
  uint2 o;
  o.x = pack2bf(v.x, v.y);
  o.y = pack2bf(v.z, v.w);
  ((uint2*)xbf)[i] = o;
}

// ---- cast all weights to bf16; shared expert becomes expert 8 ----
// region 0: gwbf[9][H][D]  (src gate_w / sh_gate_w)
// region 1: uwbf[9][H][D]  (src up_w / sh_up_w)
// region 2: dwbf[9][D][H]  (src down_w / sh_down_w)
#define VR 4718592   // vec4 per region = 9*2048*1024/4
#define VE 4194304   // vec4 expert part = 8*2048*1024/4
__global__ __launch_bounds__(256) void cast_w_kernel(
    const float* __restrict__ g, const float* __restrict__ u, const float* __restrict__ dn,
    const float* __restrict__ shg, const float* __restrict__ shu, const float* __restrict__ shd,
    unsigned short* __restrict__ outw) {
  unsigned i = blockIdx.x * 256 + threadIdx.x;   // vec4 index, < 3*VR
  unsigned r = i / VR;
  unsigned j = i - r * VR;
  const float* eb = (r == 0) ? g : (r == 1) ? u : dn;
  const float* sb = (r == 0) ? shg : (r == 1) ? shu : shd;
  const float* src = (j < VE) ? eb + 4ull * j : sb + 4ull * (j - VE);
  float4 v = *(const float4*)src;
  uint2 o;
  o.x = pack2bf(v.x, v.y);
  o.y = pack2bf(v.z, v.w);
  ((uint2*)outw)[i] = o;
}

// ---- router: fp32 logits, top2, softmax weights, z-loss + load-balance stats ----
__global__ __launch_bounds__(256) void router_kernel(
    const float* __restrict__ x, const float* __restrict__ rw, const float* __restrict__ rb,
    int* __restrict__ idxbuf, float* __restrict__ twbuf, Stats* __restrict__ st) {
  int lane = threadIdx.x & 63;
  int wv = threadIdx.x >> 6;
  int n = blockIdx.x * 4 + wv;

  float acc[NE];
#pragma unroll
  for (int e = 0; e < NE; ++e) acc[e] = 0.f;

  const float4* x4 = (const float4*)(x + (size_t)n * DIM);
#pragma unroll
  for (int q = 0; q < 4; ++q) {
    float4 xv = x4[q * 64 + lane];
#pragma unroll
    for (int e = 0; e < NE; ++e) {
      const float4* w4 = (const float4*)(rw + (size_t)e * DIM);
      float4 wvv = w4[q * 64 + lane];
      acc[e] += xv.x * wvv.x + xv.y * wvv.y + xv.z * wvv.z + xv.w * wvv.w;
    }
  }
#pragma unroll
  for (int off = 32; off; off >>= 1) {
#pragma unroll
    for (int e = 0; e < NE; ++e) acc[e] += __shfl_xor(acc[e], off);
  }

  float mx = acc[0];
#pragma unroll
  for (int e = 1; e < NE; ++e) mx = fmaxf(mx, acc[e]);
  float pr[NE];
  float es = 0.f;
#pragma unroll
  for (int e = 0; e < NE; ++e) { pr[e] = __expf(acc[e] - mx); es += pr[e]; }
  float inv = 1.f / es;
#pragma unroll
  for (int e = 0; e < NE; ++e) pr[e] *= inv;
  float z = mx + __logf(es);

  float b0 = -1e30f; int i0 = 0;
#pragma unroll
  for (int e = 0; e < NE; ++e) {
    float bb = acc[e] + rb[e];
    if (bb > b0) { b0 = bb; i0 = e; }
  }
  float b1 = -1e30f; int i1 = 0;
#pragma unroll
  for (int e = 0; e < NE; ++e) {
    if (e == i0) continue;
    float bb = acc[e] + rb[e];
    if (bb > b1) { b1 = bb; i1 = e; }
  }
  float l0 = acc[i0], l1 = acc[i1];
  float m2 = fmaxf(l0, l1);
  float e0 = __expf(l0 - m2), e1 = __expf(l1 - m2);
  float den = 1.f / (e0 + e1);
  float w0 = e0 * den, w1 = e1 * den;

  __shared__ float redp[4][9];
  __shared__ int redc[4][8];
  if (lane == 0) {
    idxbuf[n * 2] = i0; idxbuf[n * 2 + 1] = i1;
    twbuf[n * 2] = w0;  twbuf[n * 2 + 1] = w1;
#pragma unroll
    for (int e = 0; e < NE; ++e) redp[wv][e] = pr[e];
    redp[wv][8] = z * z;
#pragma unroll
    for (int e = 0; e < NE; ++e) redc[wv][e] = (e == i0) + (e == i1);
  }
  __syncthreads();
  int t = threadIdx.x;
  if (t < 9) {
    float s = redp[0][t] + redp[1][t] + redp[2][t] + redp[3][t];
    if (t < 8) atomicAdd(&st->psum[t], s);
    else       atomicAdd(&st->z2, s);
  } else if (t >= 16 && t < 24) {
    int e = t - 16;
    atomicAdd(&st->counts[e], redc[0][e] + redc[1][e] + redc[2][e] + redc[3][e]);
  }
}

// ---- scan: expert offsets + scalar outputs ----
__global__ void scan_kernel(Stats* __restrict__ st, float* __restrict__ out) {
  if (threadIdx.x == 0 && blockIdx.x == 0) {
    int o = 0;
#pragma unroll
    for (int e = 0; e < NE; ++e) { st->offs[e] = o; o += st->counts[e]; }
    st->offs[NE] = o;              // 4096
    st->offs[NE + 1] = o + N_TOK;  // 6144
    float zl = st->z2 / (float)N_TOK * 1e-4f;
    float lb = 0.f;
#pragma unroll
    for (int e = 0; e < NE; ++e)
      lb += (st->psum[e] / (float)N_TOK) * ((float)st->counts[e] / (float)N_TOK);
    lb *= (float)NE;
    out[OUT_HID + 0] = 0.f;
    out[OUT_HID + 1] = zl;
    out[OUT_HID + 2] = lb;
  }
}

// ---- scatter: per-expert assignment lists (+ shared as expert 8) ----
__global__ __launch_bounds__(256) void scatter_kernel(
    const int* __restrict__ idxbuf, const float* __restrict__ twbuf,
    Stats* __restrict__ st, int* __restrict__ tok, float* __restrict__ wl) {
  int n = blockIdx.x * 256 + threadIdx.x;
#pragma unroll
  for (int k = 0; k < 2; ++k) {
    int e = idxbuf[n * 2 + k];
    int pos = st->offs[e] + atomicAdd(&st->fill[e], 1);
    tok[pos] = n;
    wl[pos] = twbuf[n * 2 + k];
  }
  tok[A_SHARED + n] = n;
  wl[A_SHARED + n] = 1.f;
}

// ---- gate+up grouped GEMM, 128x128 tile, global_load_lds staging ----
// LDS layout: tile[128][32] bf16, chunk-swizzled: LDS chunk c of row r holds
// global k-chunk c^(r&3) (chunks of 8 bf16 = 16B).
__global__ __launch_bounds__(256, 2) void gateup_kernel(
    const unsigned short* __restrict__ gwbf, const unsigned short* __restrict__ uwbf,
    const unsigned short* __restrict__ xbf, const int* __restrict__ tok,
    const Stats* __restrict__ st, unsigned short* __restrict__ hbuf) {
  int e = blockIdx.z;
  int seg0 = st->offs[e];
  int cnt = st->offs[e + 1] - seg0;
  int m0 = blockIdx.x * 128;
  if (m0 >= cnt) return;
  int n0 = blockIdx.y * 128;

  __shared__ alignas(16) unsigned short As[128 * 32];
  __shared__ alignas(16) unsigned short Bg[128 * 32];
  __shared__ alignas(16) unsigned short Bu[128 * 32];

  int tid = threadIdx.x, l = tid & 63, w = tid >> 6;
  int wr = w >> 1, wc = w & 1;

  // staging source pointers (2 slabs of 16 rows per wave)
  int sub = l >> 2;                  // row within slab
  int cg = (l & 3) ^ (sub & 3);      // swizzled global chunk
  const unsigned short* ap[2];
  const unsigned short* gp[2];
  const unsigned short* up[2];
#pragma unroll
  for (int q = 0; q < 2; ++q) {
    int row = (w * 2 + q) * 16 + sub;
    int ar = m0 + row; if (ar > cnt - 1) ar = cnt - 1;
    ap[q] = xbf + (size_t)tok[seg0 + ar] * DIM + cg * 8;
    size_t wb = (size_t)e * HID * DIM + (size_t)(n0 + row) * DIM + cg * 8;
    gp[q] = gwbf + wb;
    up[q] = uwbf + wb;
  }

  v4f accg[4][4], accu[4][4];
#pragma unroll
  for (int mi = 0; mi < 4; ++mi)
#pragma unroll
    for (int ni = 0; ni < 4; ++ni) {
      accg[mi][ni] = (v4f){0.f, 0.f, 0.f, 0.f};
      accu[mi][ni] = (v4f){0.f, 0.f, 0.f, 0.f};
    }

  int kc = l >> 4;
  int rsw = ((kc ^ (l & 3)) * 8);    // swizzled LDS chunk offset (elements)

  for (int k0 = 0; k0 < DIM; k0 += 32) {
    async_lds16(ap[0] + k0, &As[(w * 2 + 0) * 512]);
    async_lds16(ap[1] + k0, &As[(w * 2 + 1) * 512]);
    async_lds16(gp[0] + k0, &Bg[(w * 2 + 0) * 512]);
    async_lds16(gp[1] + k0, &Bg[(w * 2 + 1) * 512]);
    async_lds16(up[0] + k0, &Bu[(w * 2 + 0) * 512]);
    async_lds16(up[1] + k0, &Bu[(w * 2 + 1) * 512]);
    __syncthreads();

    v8s af[4], bgf[4], buf[4];
#pragma unroll
    for (int mi = 0; mi < 4; ++mi) {
      int r = wr * 64 + mi * 16 + (l & 15);
      af[mi] = *(const v8s*)&As[r * 32 + rsw];
    }
#pragma unroll
    for (int ni = 0; ni < 4; ++ni) {
      int r = wc * 64 + ni * 16 + (l & 15);
      bgf[ni] = *(const v8s*)&Bg[r * 32 + rsw];
      buf[ni] = *(const v8s*)&Bu[r * 32 + rsw];
    }
#pragma unroll
    for (int mi = 0; mi < 4; ++mi)
#pragma unroll
      for (int ni = 0; ni < 4; ++ni) {
        accg[mi][ni] = __builtin_amdgcn_mfma_f32_16x16x32_bf16(af[mi], bgf[ni], accg[mi][ni], 0, 0, 0);
        accu[mi][ni] = __builtin_amdgcn_mfma_f32_16x16x32_bf16(af[mi], buf[ni], accu[mi][ni], 0, 0, 0);
      }
    __syncthreads();
  }

  int col = l & 15, rq = (l >> 4) * 4;
#pragma unroll
  for (int mi = 0; mi < 4; ++mi) {
#pragma unroll
    for (int rr = 0; rr < 4; ++rr) {
      int rl = wr * 64 + mi * 16 + rq + rr;
      if (m0 + rl < cnt) {
        size_t rowb = (size_t)(seg0 + m0 + rl) * HID + n0 + wc * 64;
#pragma unroll
        for (int ni = 0; ni < 4; ++ni) {
          float g = accg[mi][ni][rr], u = accu[mi][ni][rr];
          hbuf[rowb + ni * 16 + col] = f2bf(g * u / (1.f + __expf(-g)));
        }
      }
    }
  }
}

// ---- down grouped GEMM: out[tok] += w * (h Dw^T), 128x128 tile ----
__global__ __launch_bounds__(256, 2) void down_kernel(
    const unsigned short* __restrict__ dwbf, const unsigned short* __restrict__ hbuf,
    const int* __restrict__ tok, const float* __restrict__ wl,
    const Stats* __restrict__ st, float* __restrict__ out) {
  int e = blockIdx.z;
  int seg0 = st->offs[e];
  int cnt = st->offs[e + 1] - seg0;
  int m0 = blockIdx.x * 128;
  if (m0 >= cnt) return;
  int n0 = blockIdx.y * 128;   // over DIM

  __shared__ alignas(16) unsigned short As[128 * 32];
  __shared__ alignas(16) unsigned short Bs[128 * 32];

  int tid = threadIdx.x, l = tid & 63, w = tid >> 6;
  int wr = w >> 1, wc = w & 1;

  int sub = l >> 2;
  int cg = (l & 3) ^ (sub & 3);
  const unsigned short* ap[2];
  const unsigned short* bp[2];
#pragma unroll
  for (int q = 0; q < 2; ++q) {
    int row = (w * 2 + q) * 16 + sub;
    int ar = m0 + row; if (ar > cnt - 1) ar = cnt - 1;
    ap[q] = hbuf + (size_t)(seg0 + ar) * HID + cg * 8;
    bp[q] = dwbf + (size_t)e * DIM * HID + (size_t)(n0 + row) * HID + cg * 8;
  }

  v4f acc[4][4];
#pragma unroll
  for (int mi = 0; mi < 4; ++mi)
#pragma unroll
    for (int ni = 0; ni < 4; ++ni) acc[mi][ni] = (v4f){0.f, 0.f, 0.f, 0.f};

  int kc = l >> 4;
  int rsw = ((kc ^ (l & 3)) * 8);

  for (int k0 = 0; k0 < HID; k0 += 32) {
    async_lds16(ap[0] + k0, &As[(w * 2 + 0) * 512]);
    async_lds16(ap[1] + k0, &As[(w * 2 + 1) * 512]);
    async_lds16(bp[0] + k0, &Bs[(w * 2 + 0) * 512]);
    async_lds16(bp[1] + k0, &Bs[(w * 2 + 1) * 512]);
    __syncthreads();

    v8s af[4], bf[4];
#pragma unroll
    for (int mi = 0; mi < 4; ++mi) {
      int r = wr * 64 + mi * 16 + (l & 15);
      af[mi] = *(const v8s*)&As[r * 32 + rsw];
    }
#pragma unroll
    for (int ni = 0; ni < 4; ++ni) {
      int r = wc * 64 + ni * 16 + (l & 15);
      bf[ni] = *(const v8s*)&Bs[r * 32 + rsw];
    }
#pragma unroll
    for (int mi = 0; mi < 4; ++mi)
#pragma unroll
      for (int ni = 0; ni < 4; ++ni)
        acc[mi][ni] = __builtin_amdgcn_mfma_f32_16x16x32_bf16(af[mi], bf[ni], acc[mi][ni], 0, 0, 0);
    __syncthreads();
  }

  int col = l & 15, rq = (l >> 4) * 4;
#pragma unroll
  for (int mi = 0; mi < 4; ++mi) {
#pragma unroll
    for (int rr = 0; rr < 4; ++rr) {
      int rl = wr * 64 + mi * 16 + rq + rr;
      if (m0 + rl < cnt) {
        int t = tok[seg0 + m0 + rl];
        float wgt = wl[seg0 + m0 + rl];
        float* ob = out + (size_t)t * DIM + n0 + wc * 64;
#pragma unroll
        for (int ni = 0; ni < 4; ++ni)
          atomicAdd(ob + ni * 16 + col, acc[mi][ni][rr] * wgt);
      }
    }
  }
}

extern "C" void kernel_launch(void* const* d_in, const int* in_sizes, int n_in,
                              void* d_out, int out_size, void* d_ws, size_t ws_size,
                              hipStream_t stream) {
  const float* x   = (const float*)d_in[0];
  const float* rw  = (const float*)d_in[1];
  const float* rb  = (const float*)d_in[2];
  const float* gw  = (const float*)d_in[3];
  const float* uw  = (const float*)d_in[4];
  const float* dw  = (const float*)d_in[5];
  const float* shg = (const float*)d_in[6];
  const float* shu = (const float*)d_in[7];
  const float* shd = (const float*)d_in[8];
  float* out = (float*)d_out;
  char* ws = (char*)d_ws;

  unsigned short* xbf  = (unsigned short*)(ws + OFF_XBF);
  unsigned short* hbuf = (unsigned short*)(ws + OFF_H);
  unsigned short* gwbf = (unsigned short*)(ws + OFF_GW);
  unsigned short* uwbf = (unsigned short*)(ws + OFF_UW);
  unsigned short* dwbf = (unsigned short*)(ws + OFF_DW);
  int*   tok  = (int*)(ws + OFF_TOK);
  float* wl   = (float*)(ws + OFF_WL);
  int*   idxb = (int*)(ws + OFF_IDX);
  float* twb  = (float*)(ws + OFF_TW);
  Stats* st   = (Stats*)(ws + OFF_STATS);

  hipMemsetAsync(d_out, 0, (size_t)out_size * sizeof(float), stream);
  hipMemsetAsync(st, 0, sizeof(Stats), stream);

  cast_x_kernel<<<2048, 256, 0, stream>>>(x, xbf);
  cast_w_kernel<<<55296, 256, 0, stream>>>(gw, uw, dw, shg, shu, shd, gwbf);
  router_kernel<<<512, 256, 0, stream>>>(x, rw, rb, idxb, twb, st);
  scan_kernel<<<1, 64, 0, stream>>>(st, out);
  scatter_kernel<<<8, 256, 0, stream>>>(idxb, twb, st, tok, wl);
  gateup_kernel<<<dim3(16, 16, 9), 256, 0, stream>>>(gwbf, uwbf, xbf, tok, st, hbuf);
  down_kernel<<<dim3(16, 8, 9), 256, 0, stream>>>(dwbf, hbuf, tok, wl, st, out);
}